// Round 11
// baseline (564.685 us; speedup 1.0000x reference)
//
#include <hip/hip_runtime.h>
#include <hip/hip_bf16.h>

typedef __attribute__((ext_vector_type(8))) short short8;
typedef __attribute__((ext_vector_type(4))) short short4v;
typedef __attribute__((ext_vector_type(4))) float floatx4;

#define EDIM 256
#define HDIM 512
#define LDIM 16
#define NCOL 2048
#define KC 32       // k-chunk

__device__ __forceinline__ float fsigmoid(float x){ return 1.0f/(1.0f+__expf(-x)); }
__device__ __forceinline__ float ftanh(float x){ return 2.0f/(1.0f+__expf(-2.0f*x))-1.0f; }
__device__ __forceinline__ float bf2f(short s){
    union { unsigned u; float f; } cv; cv.u = ((unsigned)(unsigned short)s) << 16; return cv.f;
}
__device__ __forceinline__ unsigned short f2bf_bits(float v){
    union { __hip_bfloat16 h; unsigned short u; } cv;
    cv.h = __float2bfloat16(v); return cv.u;
}

// ---- coherent (L2-bypassing, write-through) primitives; compiler-managed.
__device__ __forceinline__ short8 aload16(const short* p) {
    union { unsigned long long q[2]; short8 s; } u;
    u.q[0] = __hip_atomic_load((const unsigned long long*)p,
                               __ATOMIC_RELAXED, __HIP_MEMORY_SCOPE_AGENT);
    u.q[1] = __hip_atomic_load((const unsigned long long*)p + 1,
                               __ATOMIC_RELAXED, __HIP_MEMORY_SCOPE_AGENT);
    return u.s;
}
__device__ __forceinline__ void astore_bf16(short* p, float v) {
    __hip_atomic_store((unsigned short*)p, f2bf_bits(v),
                       __ATOMIC_RELAXED, __HIP_MEMORY_SCOPE_AGENT);
}

__device__ __forceinline__ bool detect_bf16(const short* p) {
    // fp32 buffers' even shorts are low mantissa bits (~uniform) -> exponent
    // field frequently > 0x7B; true bf16 U(-.05,.05) weights never exceed it.
    bool bf = true;
    for (int i = 0; i < 64; i += 2) {
        int e = (((unsigned short)p[i]) >> 7) & 0xFF;
        if (e > 0x7B) bf = false;
    }
    return bf;
}

// ---------------------------------------------------------------------------
// W_hh -> bf16 (copy if already bf16). Also zeroes the group-barrier
// counters (bar[mt*32], 128 B apart) used by lstm_fused.
// ---------------------------------------------------------------------------
__global__ void conv_whh(const void* __restrict__ whhp, short* __restrict__ whh_o,
                         unsigned* __restrict__ bar) {
    if (blockIdx.x == 0)
        for (int i = threadIdx.x; i < 512; i += 256) bar[i] = 0u;
    bool bf = detect_bf16((const short*)whhp);
    int tid = blockIdx.x * blockDim.x + threadIdx.x;
    int stride = gridDim.x * blockDim.x;
    if (bf) {
        const short* s = (const short*)whhp;
        for (int i = tid; i < NCOL * HDIM; i += stride) whh_o[i] = s[i];
    } else {
        const float* s = (const float*)whhp;
        for (int i = tid; i < NCOL * HDIM; i += stride)
            ((__hip_bfloat16*)whh_o)[i] = __float2bfloat16(s[i]);
    }
}

// ---------------------------------------------------------------------------
// xg[id][j][g] = emb[id] . W_ih[g*512+j] + b_ih + b_hh   (bf16 out)
// Layout is [id][j][4 gates] so the LSTM epilogue gathers one 8B vector.
// ---------------------------------------------------------------------------
__global__ void build_xg(const void* __restrict__ embp, const void* __restrict__ wihp,
                         const void* __restrict__ bihp, const void* __restrict__ bhhp,
                         short* __restrict__ xg)
{
    __shared__ float es[16][EDIM];        // 16 KB
    __shared__ float wsm[32][EDIM + 1];   // 32.1 KB (pad breaks bank conflicts)
    bool bf = detect_bf16((const short*)wihp);
    const int idt = blockIdx.x, ct = blockIdx.y, tt = threadIdx.x;

    if (bf) {
        const __hip_bfloat16* e = (const __hip_bfloat16*)embp;
        const __hip_bfloat16* wv = (const __hip_bfloat16*)wihp;
        for (int p = 0; p < 16; ++p) es[p][tt] = __bfloat162float(e[(idt*16+p)*EDIM + tt]);
        for (int p = 0; p < 32; ++p) wsm[p][tt] = __bfloat162float(wv[(ct*32+p)*EDIM + tt]);
    } else {
        const float* e = (const float*)embp;
        const float* wv = (const float*)wihp;
        for (int p = 0; p < 16; ++p) es[p][tt] = e[(idt*16+p)*EDIM + tt];
        for (int p = 0; p < 32; ++p) wsm[p][tt] = wv[(ct*32+p)*EDIM + tt];
    }
    __syncthreads();

    const int col_l = tt & 31, grp = tt >> 5;   // 8 groups x 2 ids
    const int col = ct * 32 + col_l;            // 0..2047, gate-major
    float bsum = bf ? (__bfloat162float(((const __hip_bfloat16*)bihp)[col]) +
                       __bfloat162float(((const __hip_bfloat16*)bhhp)[col]))
                    : (((const float*)bihp)[col] + ((const float*)bhhp)[col]);
    float a0 = 0.f, a1 = 0.f;
    for (int k = 0; k < EDIM; ++k) {
        float wv = wsm[col_l][k];
        a0 += es[grp*2+0][k] * wv;
        a1 += es[grp*2+1][k] * wv;
    }
    const int jj = col & (HDIM - 1), gsel = col >> 9;
    ((__hip_bfloat16*)xg)[(idt*16 + grp*2 + 0)*NCOL + jj*4 + gsel] = __float2bfloat16(a0 + bsum);
    ((__hip_bfloat16*)xg)[(idt*16 + grp*2 + 1)*NCOL + jj*4 + gsel] = __float2bfloat16(a1 + bsum);
}

// ---------------------------------------------------------------------------
// Fused LSTM, 2-blocks-per-CU edition (occupancy 23%->~45%):
//  - grid 512 = 16 mt x 32 jt16; block = 256 chains x (4 gates x 16 j).
//    LDS 80 KB (Bs 64 + As 16) -> 2 independent blocks per CU; one block's
//    MFMA/epilogue covers the other's flag/L3 stalls (the ~50% idle in r9).
//  - __launch_bounds__(512,4) pins VGPR<=128 so 2 blocks/CU is guaranteed
//    (all 512 blocks co-resident -> group barrier deadlock-free).
//  - As is SINGLE-buffered and WAVE-PRIVATE (wave w stages+reads only rows
//    w*32..w*32+31): per-wave DS FIFO (read kc issued before write kc+1)
//    makes the k-loop 100% barrier-free. Distance-2 register staging.
//  - h exchange: r9-proven relaxed agent atomics (write-through stores,
//    L2-bypass loads, zero cache maintenance); step barrier = pure relaxed
//    counter, target 32 blocks per mt group.
// ---------------------------------------------------------------------------
__launch_bounds__(512, 4)
__global__ void lstm_fused(const int* __restrict__ seq, const int* __restrict__ lens,
                           const short* __restrict__ whh,   // bf16 [2048][512]
                           const short* __restrict__ xg,    // bf16 [256][512][4]
                           short* __restrict__ hb0, short* __restrict__ hb1,
                           float* __restrict__ out,         // fp32 [4096][512]
                           unsigned* __restrict__ bar)      // [16*32] padded counters
{
    __shared__ __align__(16) short Bs[64 * 512];   // 64 KB, swizzled
    __shared__ __align__(16) short As[256 * KC];   // 16 KB, wave-private slices

    const int f  = blockIdx.x;
    // mt from low 4 bits (same-mt blocks land on one XCD: f%8 fixed per mt).
    const int mt = ((f & 7) << 1) | ((f >> 3) & 1);
    const int jt = f >> 4;                // 0..31, 16-j slab
    const int tid = threadIdx.x;
    const int w = tid >> 6, lane = tid & 63;
    const int q = lane >> 4, ln = lane & 15;
    const int jglob = jt * 16 + ln;

    // ---- stage W_hh slab into LDS once: Bs row g*16+jl <- whh[g*512+jt*16+jl]
    // swizzle: elem col c stored at c ^ ((row&7)<<3)
#pragma unroll
    for (int it = 0; it < 8; ++it) {
        int task = it * 512 + tid;            // 4096 tasks of 16 B
        int row = task >> 6, seg = task & 63;
        int grow = (row >> 4) * HDIM + jt * 16 + (row & 15);
        short8 v = *(const short8*)(whh + grow * HDIM + seg * 8);
        *(short8*)&Bs[row * 512 + ((seg * 8) ^ ((row & 7) << 3))] = v;
    }

    const int chainbase = mt * 256 + w * 32 + q * 4;
    const int obase = chainbase * HDIM + jglob;
    unsigned* __restrict__ barp = bar + (mt << 5);

    // wave-private staging constants: lane covers rows srow0 and srow0+16
    const int srow0 = w * 32 + (lane >> 2), sseg = lane & 3;
    const int gA0 = srow0 * HDIM + sseg * 8;            // + mt*256*HDIM at use
    const int gA1 = gA0 + 16 * HDIM;
    const int lA0 = srow0 * KC + ((sseg * 8) ^ ((srow0 & 3) << 3));
    const int lA1 = lA0 + 16 * KC;                      // (srow0+16)&3 == srow0&3

    // packed lens (values 1..16 fit a byte) -> 2 VGPRs; cells e: mf=e>>2, r=e&3
    unsigned lnspk[2] = {0u, 0u};
#pragma unroll
    for (int e = 0; e < 8; ++e)
        lnspk[e >> 2] |= ((unsigned)lens[chainbase + (e >> 2) * 16 + (e & 3)] & 0xFFu)
                         << ((e & 3) * 8);

    float c_st[8], h_st[8];
#pragma unroll
    for (int e = 0; e < 8; ++e) { c_st[e] = 0.f; h_st[e] = 0.f; }

    int ids[8];
#pragma unroll
    for (int e = 0; e < 8; ++e)
        ids[e] = seq[(chainbase + (e >> 2) * 16 + (e & 3)) * LDIM + 0];

    for (int t = 0; t < LDIM; ++t) {
        const short* hr = (t & 1) ? hb1 : hb0;   // written at step t-1
        short* hw       = (t & 1) ? hb0 : hb1;
        const bool notlast = (t < LDIM - 1);

        floatx4 acc[4][2];  // [gate][mfrag: rows w*32+mf*16]
#pragma unroll
        for (int g = 0; g < 4; ++g)
#pragma unroll
            for (int mf = 0; mf < 2; ++mf) acc[g][mf] = (floatx4){0.f, 0.f, 0.f, 0.f};

        if (t > 0) {
            const short* abase = hr + (size_t)mt * 256 * HDIM;
            short8 rq[2][2];   // distance-2 parity pipeline
            rq[0][0] = aload16(abase + gA0);
            rq[0][1] = aload16(abase + gA1);
            rq[1][0] = aload16(abase + gA0 + KC);
            rq[1][1] = aload16(abase + gA1 + KC);
            *(short8*)&As[lA0] = rq[0][0];     // ds_write chunk 0
            *(short8*)&As[lA1] = rq[0][1];
#pragma unroll
            for (int kc = 0; kc < 16; ++kc) {
                // ds_read chunk kc (FIFO: issued before the kc+1 write below)
                short8 af[2], bfr[4];
#pragma unroll
                for (int mf = 0; mf < 2; ++mf)
                    af[mf] = *(const short8*)&As[(w * 32 + mf * 16 + ln) * KC +
                                                 ((q * 8) ^ ((ln & 3) << 3))];
#pragma unroll
                for (int g = 0; g < 4; ++g)
                    bfr[g] = *(const short8*)&Bs[(g * 16 + ln) * 512 +
                                                 ((kc * 32 + q * 8) ^ ((ln & 7) << 3))];
                // ds_write chunk kc+1 (regs loaded at kc-1)
                if (kc < 15) {
                    *(short8*)&As[lA0] = rq[(kc + 1) & 1][0];
                    *(short8*)&As[lA1] = rq[(kc + 1) & 1][1];
                }
                // issue loads for chunk kc+2
                if (kc < 14) {
                    rq[kc & 1][0] = aload16(abase + gA0 + (kc + 2) * KC);
                    rq[kc & 1][1] = aload16(abase + gA1 + (kc + 2) * KC);
                }
                __builtin_amdgcn_s_setprio(1);
#pragma unroll
                for (int g = 0; g < 4; ++g)
#pragma unroll
                    for (int mf = 0; mf < 2; ++mf)
                        acc[g][mf] = __builtin_amdgcn_mfma_f32_16x16x32_bf16(
                            af[mf], bfr[g], acc[g][mf], 0, 0, 0);
                __builtin_amdgcn_s_setprio(0);
            }
        }

        // ---- epilogue. C/D: col=ln (j), row=q*4+r (chain). xg inline (L2).
#pragma unroll
        for (int e = 0; e < 8; ++e) {
            const int mf = e >> 2, r = e & 3;
            short4v xv = *(const short4v*)(xg + ids[e] * NCOL + jglob * 4);
            float p0 = acc[0][mf][r] + bf2f(xv[0]);
            float p1 = acc[1][mf][r] + bf2f(xv[1]);
            float p2 = acc[2][mf][r] + bf2f(xv[2]);
            float p3 = acc[3][mf][r] + bf2f(xv[3]);
            float ig = fsigmoid(p0);
            float fg = fsigmoid(p1);
            float gg = ftanh(p2);
            float og = fsigmoid(p3);
            float cn = fg * c_st[e] + ig * gg;
            float hn = og * ftanh(cn);
            bool mk = (int)((lnspk[e >> 2] >> ((e & 3) * 8)) & 0xFFu) > t;
            float hsv = mk ? hn : h_st[e];
            float csv = mk ? cn : c_st[e];
            h_st[e] = hsv; c_st[e] = csv;
            int off = obase + (mf * 16 + r) * HDIM;
            if (notlast) astore_bf16(hw + off, hsv);   // coherent write-through
            else         out[off] = hsv;               // final h, fp32
        }

        // ---- step barrier among the 32 jt-blocks of this mt: pure relaxed
        // counter (r9-proven). __syncthreads drains all waves' h stores.
        if (notlast) {
            __syncthreads();
#pragma unroll
            for (int e = 0; e < 8; ++e)   // seq ids for t+1 (read-only, cached)
                ids[e] = seq[(chainbase + (e >> 2) * 16 + (e & 3)) * LDIM + t + 1];
            if (tid == 0) {
                __hip_atomic_fetch_add(barp, 1u, __ATOMIC_RELAXED,
                                       __HIP_MEMORY_SCOPE_AGENT);
                const unsigned target = 32u * (unsigned)(t + 1);
                while (__hip_atomic_load(barp, __ATOMIC_RELAXED,
                                         __HIP_MEMORY_SCOPE_AGENT) < target)
                    __builtin_amdgcn_s_sleep(2);
            }
            __syncthreads();
        }
    }
}

extern "C" void kernel_launch(void* const* d_in, const int* in_sizes, int n_in,
                              void* d_out, int out_size, void* d_ws, size_t ws_size,
                              hipStream_t stream) {
    const int* seq  = (const int*)d_in[0];
    const int* lens = (const int*)d_in[1];

    // ws: h_even 4M | h_odd 4M | xg 1M | whh_bf 2M | bar 2KB (<= proven 11.14M)
    char* w = (char*)d_ws;
    short* h_even = (short*)w;
    short* h_odd  = (short*)(w + 4u*1024*1024);
    short* xg     = (short*)(w + 8u*1024*1024);
    short* whh_bf = (short*)(w + 9u*1024*1024);
    unsigned* bar = (unsigned*)(w + 11u*1024*1024);
    float* outp   = (float*)d_out;

    conv_whh<<<512, 256, 0, stream>>>(d_in[4], whh_bf, bar);
    build_xg<<<dim3(16, 64), 256, 0, stream>>>(d_in[2], d_in[3], d_in[5], d_in[6], xg);
    lstm_fused<<<512, 512, 0, stream>>>(seq, lens, whh_bf, xg, h_even, h_odd, outp, bar);
}

// Round 12
// 433.239 us; speedup vs baseline: 1.3034x; 1.3034x over previous
//
#include <hip/hip_runtime.h>
#include <hip/hip_bf16.h>

typedef __attribute__((ext_vector_type(8))) short short8;
typedef __attribute__((ext_vector_type(4))) short short4v;
typedef __attribute__((ext_vector_type(4))) float floatx4;

#define EDIM 256
#define HDIM 512
#define LDIM 16
#define NCOL 2048
#define BM 256      // chains per block
#define KC 32       // k-chunk

__device__ __forceinline__ float fsigmoid(float x){ return 1.0f/(1.0f+__expf(-x)); }
__device__ __forceinline__ float ftanh(float x){ return 2.0f/(1.0f+__expf(-2.0f*x))-1.0f; }
__device__ __forceinline__ float bf2f(short s){
    union { unsigned u; float f; } cv; cv.u = ((unsigned)(unsigned short)s) << 16; return cv.f;
}
__device__ __forceinline__ unsigned short f2bf_bits(float v){
    union { __hip_bfloat16 h; unsigned short u; } cv;
    cv.h = __float2bfloat16(v); return cv.u;
}

// 16B coherent load: two agent-scope RELAXED atomic u64 loads. Compiler-managed
// (emits global_load_dwordx2 with coherence bits + proper s_waitcnt) -- no
// inline-asm load hazard. Bypasses non-coherent L2 => sees write-through h
// stores from ANY XCD without any fence/invalidate.
__device__ __forceinline__ short8 aload16(const short* p) {
    union { unsigned long long q[2]; short8 s; } u;
    u.q[0] = __hip_atomic_load((const unsigned long long*)p,
                               __ATOMIC_RELAXED, __HIP_MEMORY_SCOPE_AGENT);
    u.q[1] = __hip_atomic_load((const unsigned long long*)p + 1,
                               __ATOMIC_RELAXED, __HIP_MEMORY_SCOPE_AGENT);
    return u.s;
}
// Coherent bf16 store (write-through; single-copy-atomic 2B store).
__device__ __forceinline__ void astore_bf16(short* p, float v) {
    __hip_atomic_store((unsigned short*)p, f2bf_bits(v),
                       __ATOMIC_RELAXED, __HIP_MEMORY_SCOPE_AGENT);
}
// LDS-only barrier: waves sync WITHOUT draining vmcnt -> global prefetch
// loads stay in flight across chunk boundaries (T4 counted-vmcnt pattern).
__device__ __forceinline__ void lds_barrier() {
    asm volatile("s_waitcnt lgkmcnt(0)" ::: "memory");
    __builtin_amdgcn_s_barrier();
}

__device__ __forceinline__ bool detect_bf16(const short* p) {
    // fp32 buffers' even shorts are low mantissa bits (~uniform) -> exponent
    // field frequently > 0x7B; true bf16 U(-.05,.05) weights never exceed it.
    bool bf = true;
    for (int i = 0; i < 64; i += 2) {
        int e = (((unsigned short)p[i]) >> 7) & 0xFF;
        if (e > 0x7B) bf = false;
    }
    return bf;
}

// ---------------------------------------------------------------------------
// W_hh -> bf16 (copy if already bf16). Also zeroes the group-barrier
// counters used by lstm_fused (workspace is poisoned between runs).
// bar layout: counter for mt at bar[mt*32] (128 B apart, no false sharing).
// ---------------------------------------------------------------------------
__global__ void conv_whh(const void* __restrict__ whhp, short* __restrict__ whh_o,
                         unsigned* __restrict__ bar) {
    if (blockIdx.x == 0)
        for (int i = threadIdx.x; i < 512; i += 256) bar[i] = 0u;
    bool bf = detect_bf16((const short*)whhp);
    int tid = blockIdx.x * blockDim.x + threadIdx.x;
    int stride = gridDim.x * blockDim.x;
    if (bf) {
        const short* s = (const short*)whhp;
        for (int i = tid; i < NCOL * HDIM; i += stride) whh_o[i] = s[i];
    } else {
        const float* s = (const float*)whhp;
        for (int i = tid; i < NCOL * HDIM; i += stride)
            ((__hip_bfloat16*)whh_o)[i] = __float2bfloat16(s[i]);
    }
}

// ---------------------------------------------------------------------------
// xg[id][j][g] = emb[id] . W_ih[g*512+j] + b_ih + b_hh   (bf16 out)
// Layout is [id][j][4 gates] so the LSTM epilogue gathers one 8B vector.
// ---------------------------------------------------------------------------
__global__ void build_xg(const void* __restrict__ embp, const void* __restrict__ wihp,
                         const void* __restrict__ bihp, const void* __restrict__ bhhp,
                         short* __restrict__ xg)
{
    __shared__ float es[16][EDIM];        // 16 KB
    __shared__ float wsm[32][EDIM + 1];   // 32.1 KB (pad breaks bank conflicts)
    bool bf = detect_bf16((const short*)wihp);
    const int idt = blockIdx.x, ct = blockIdx.y, tt = threadIdx.x;

    if (bf) {
        const __hip_bfloat16* e = (const __hip_bfloat16*)embp;
        const __hip_bfloat16* wv = (const __hip_bfloat16*)wihp;
        for (int p = 0; p < 16; ++p) es[p][tt] = __bfloat162float(e[(idt*16+p)*EDIM + tt]);
        for (int p = 0; p < 32; ++p) wsm[p][tt] = __bfloat162float(wv[(ct*32+p)*EDIM + tt]);
    } else {
        const float* e = (const float*)embp;
        const float* wv = (const float*)wihp;
        for (int p = 0; p < 16; ++p) es[p][tt] = e[(idt*16+p)*EDIM + tt];
        for (int p = 0; p < 32; ++p) wsm[p][tt] = wv[(ct*32+p)*EDIM + tt];
    }
    __syncthreads();

    const int col_l = tt & 31, grp = tt >> 5;   // 8 groups x 2 ids
    const int col = ct * 32 + col_l;            // 0..2047, gate-major
    float bsum = bf ? (__bfloat162float(((const __hip_bfloat16*)bihp)[col]) +
                       __bfloat162float(((const __hip_bfloat16*)bhhp)[col]))
                    : (((const float*)bihp)[col] + ((const float*)bhhp)[col]);
    float a0 = 0.f, a1 = 0.f;
    for (int k = 0; k < EDIM; ++k) {
        float wv = wsm[col_l][k];
        a0 += es[grp*2+0][k] * wv;
        a1 += es[grp*2+1][k] * wv;
    }
    const int jj = col & (HDIM - 1), gsel = col >> 9;
    ((__hip_bfloat16*)xg)[(idt*16 + grp*2 + 0)*NCOL + jj*4 + gsel] = __float2bfloat16(a0 + bsum);
    ((__hip_bfloat16*)xg)[(idt*16 + grp*2 + 1)*NCOL + jj*4 + gsel] = __float2bfloat16(a1 + bsum);
}

// ---------------------------------------------------------------------------
// Fully fused LSTM (round-9 champion, restored verbatim):
//  - grid 256 blocks (1/CU, co-resident), 512 thr = 8 waves.
//  - W_hh slab persistent in LDS (128 KB, XOR-swizzled).
//  - A (h_prev): block-wide burst staging into LDS dbuf, distance-2 register
//    pipeline; chunk barriers are lgkmcnt-only (T4) so staging loads stay
//    in flight across chunk boundaries.
//  - h exchanged via agent-RELAXED atomics (write-through stores, L2-bypass
//    loads; coherent through L3 for any block->XCD placement). ZERO cache
//    maintenance; step barrier is a pure relaxed counter.
//  - c/h state in registers; seq ids at step top; xg gathers prefetched in
//    the barrier-poll window (read-only).
// ---------------------------------------------------------------------------
__launch_bounds__(512, 2)
__global__ void lstm_fused(const int* __restrict__ seq, const int* __restrict__ lens,
                           const short* __restrict__ whh,   // bf16 [2048][512]
                           const short* __restrict__ xg,    // bf16 [256][512][4]
                           short* __restrict__ hb0, short* __restrict__ hb1,
                           float* __restrict__ out,         // fp32 [4096][512]
                           unsigned* __restrict__ bar)      // [16*32] padded counters
{
    __shared__ __align__(16) short Bs[128 * 512];   // 128 KB, swizzled
    __shared__ __align__(16) short As[2][BM * KC];  // 32 KB, swizzled

    const int f  = blockIdx.x;
    // XCD swizzle: all 16 jt-blocks of an mt tend to land on one XCD (perf
    // only; correctness is placement-independent).
    const int mt = ((f & 7) << 1) | ((f >> 3) & 1);
    const int jt = f >> 4;
    const int tid = threadIdx.x;
    const int wave = tid >> 6, lane = tid & 63;
    const int q = lane >> 4, ln = lane & 15;
    const int ms = wave & 3, ns = wave >> 2;
    const int jloc = ns * 16 + ln;        // 0..31 within block's j-slab
    const int jglob = jt * 32 + jloc;

    // ---- stage W_hh slab into LDS once: rows g*32+jl <- whh[g*512+jt*32+jl]
    // swizzle: elem col c stored at c ^ ((row&7)<<3)  (16B-group XOR)
#pragma unroll
    for (int it = 0; it < 16; ++it) {
        int task = it * 512 + tid;            // 8192 tasks of 16 B
        int row = task >> 6, seg = task & 63;
        int grow = (row >> 5) * HDIM + jt * 32 + (row & 31);
        short8 v = *(const short8*)(whh + grow * HDIM + seg * 8);
        *(short8*)&Bs[row * 512 + ((seg * 8) ^ ((row & 7) << 3))] = v;
    }

    const int chainbase = mt * BM + ms * 64 + q * 4;
    const int obase = chainbase * HDIM + jglob;
    unsigned* __restrict__ barp = bar + (mt << 5);

    // staging task constants: thread covers rows srow and 128+srow, 16 B each
    const int srow = tid >> 2, sseg = tid & 3;
    const int g0 = srow * HDIM + sseg * 8;           // global elem offsets
    const int g1 = (128 + srow) * HDIM + sseg * 8;
    const int l0 = srow * KC + ((sseg * 8) ^ ((srow & 3) << 3));        // LDS
    const int l1 = (128 + srow) * KC + ((sseg * 8) ^ ((srow & 3) << 3));

    // packed lens (values 1..16 fit a byte) -> 4 VGPRs
    unsigned lnspk[4] = {0u, 0u, 0u, 0u};
#pragma unroll
    for (int e = 0; e < 16; ++e)
        lnspk[e >> 2] |= ((unsigned)lens[chainbase + (e >> 2) * 16 + (e & 3)] & 0xFFu)
                         << ((e & 3) * 8);

    float c_st[16], h_st[16];
#pragma unroll
    for (int e = 0; e < 16; ++e) { c_st[e] = 0.f; h_st[e] = 0.f; }

    // prefetch t=0 ids + gate vectors (normal cached loads: read-only data)
    int idsN[16];
    short4v xv[16];
#pragma unroll
    for (int e = 0; e < 16; ++e)
        idsN[e] = seq[(chainbase + (e >> 2) * 16 + (e & 3)) * LDIM + 0];
#pragma unroll
    for (int e = 0; e < 16; ++e)
        xv[e] = *(const short4v*)(xg + idsN[e] * NCOL + jglob * 4);

    for (int t = 0; t < LDIM; ++t) {
        const short* hr = (t & 1) ? hb1 : hb0;   // written at step t-1
        short* hw       = (t & 1) ? hb0 : hb1;
        const bool notlast = (t < LDIM - 1);

        // seq ids for t+1: read-only, issue now, land during the GEMM
        if (notlast) {
#pragma unroll
            for (int e = 0; e < 16; ++e)
                idsN[e] = seq[(chainbase + (e >> 2) * 16 + (e & 3)) * LDIM + t + 1];
        }

        floatx4 acc[4][4];  // [gate][mfrag]
#pragma unroll
        for (int g = 0; g < 4; ++g)
#pragma unroll
            for (int mf = 0; mf < 4; ++mf) acc[g][mf] = (floatx4){0.f, 0.f, 0.f, 0.f};

        if (t > 0) {
            const short* abase = hr + (size_t)mt * BM * HDIM;
            // rq[parity][p] holds the chunk (of that parity) next to ds_write
            short8 rq[2][2];
            {   // prologue: chunk 0 -> LDS; chunk 1 -> regs (loads coherent)
                short8 v0 = aload16(abase + g0);
                short8 v1 = aload16(abase + g1);
                rq[1][0]  = aload16(abase + g0 + KC);
                rq[1][1]  = aload16(abase + g1 + KC);
                *(short8*)&As[0][l0] = v0;
                *(short8*)&As[0][l1] = v1;
            }
            lds_barrier();
#pragma unroll
            for (int kc = 0; kc < 16; ++kc) {
                const int b = kc & 1;
                // ds_write chunk kc+1 (regs; compiler waits vmcnt for exactly
                // these loads -- issued 2 chunks ago, latency fully covered)
                if (kc < 15) {
                    *(short8*)&As[b ^ 1][l0] = rq[(kc + 1) & 1][0];
                    *(short8*)&As[b ^ 1][l1] = rq[(kc + 1) & 1][1];
                }
                // issue global load for chunk kc+2; stays in flight across
                // the (vmcnt-free) chunk barriers below.
                if (kc < 14) {
                    rq[kc & 1][0] = aload16(abase + g0 + (kc + 2) * KC);
                    rq[kc & 1][1] = aload16(abase + g1 + (kc + 2) * KC);
                }
                // compute on buffer b
                short8 af[4], bfr[4];
#pragma unroll
                for (int mf = 0; mf < 4; ++mf)
                    af[mf] = *(const short8*)&As[b][(ms * 64 + mf * 16 + ln) * KC +
                                                    ((q * 8) ^ ((ln & 3) << 3))];
#pragma unroll
                for (int g = 0; g < 4; ++g)
                    bfr[g] = *(const short8*)&Bs[(g * 32 + jloc) * 512 +
                                                 ((kc * 32 + q * 8) ^ ((ln & 7) << 3))];
                __builtin_amdgcn_s_setprio(1);
#pragma unroll
                for (int g = 0; g < 4; ++g)
#pragma unroll
                    for (int mf = 0; mf < 4; ++mf)
                        acc[g][mf] = __builtin_amdgcn_mfma_f32_16x16x32_bf16(
                            af[mf], bfr[g], acc[g][mf], 0, 0, 0);
                __builtin_amdgcn_s_setprio(0);
                lds_barrier();   // LDS-only: global loads NOT drained (T4)
            }
        }

        // ---- epilogue: prefetched xg + cell update. C/D: col=ln, row=q*4+r
#pragma unroll
        for (int e = 0; e < 16; ++e) {
            const int mf = e >> 2, r = e & 3;
            float p0 = acc[0][mf][r] + bf2f(xv[e][0]);
            float p1 = acc[1][mf][r] + bf2f(xv[e][1]);
            float p2 = acc[2][mf][r] + bf2f(xv[e][2]);
            float p3 = acc[3][mf][r] + bf2f(xv[e][3]);
            float ig = fsigmoid(p0);
            float fg = fsigmoid(p1);
            float gg = ftanh(p2);
            float og = fsigmoid(p3);
            float cn = fg * c_st[e] + ig * gg;
            float hn = og * ftanh(cn);
            bool mk = (int)((lnspk[e >> 2] >> ((e & 3) * 8)) & 0xFFu) > t;
            float hsv = mk ? hn : h_st[e];
            float csv = mk ? cn : c_st[e];
            h_st[e] = hsv; c_st[e] = csv;
            int off = obase + (mf * 16 + r) * HDIM;
            if (notlast) astore_bf16(hw + off, hsv);   // coherent write-through
            else         out[off] = hsv;               // final h, fp32
        }

        // ---- step barrier among the 16 jt-blocks of this mt: PURE relaxed
        // counter, zero cache ops. __syncthreads drains vmcnt -> all h
        // atomic stores are globally visible (write-through) before arrive.
        if (notlast) {
            __syncthreads();
#pragma unroll
            for (int e = 0; e < 16; ++e)     // xg for t+1 (read-only, cached)
                xv[e] = *(const short4v*)(xg + idsN[e] * NCOL + jglob * 4);
            if (tid == 0) {
                __hip_atomic_fetch_add(barp, 1u, __ATOMIC_RELAXED,
                                       __HIP_MEMORY_SCOPE_AGENT);
                const unsigned target = 16u * (unsigned)(t + 1);
                while (__hip_atomic_load(barp, __ATOMIC_RELAXED,
                                         __HIP_MEMORY_SCOPE_AGENT) < target)
                    __builtin_amdgcn_s_sleep(2);
            }
            __syncthreads();
        }
    }
}

extern "C" void kernel_launch(void* const* d_in, const int* in_sizes, int n_in,
                              void* d_out, int out_size, void* d_ws, size_t ws_size,
                              hipStream_t stream) {
    const int* seq  = (const int*)d_in[0];
    const int* lens = (const int*)d_in[1];

    // ws: h_even 4M | h_odd 4M | xg 1M | whh_bf 2M | bar 2KB (<= proven 11.14M)
    char* w = (char*)d_ws;
    short* h_even = (short*)w;
    short* h_odd  = (short*)(w + 4u*1024*1024);
    short* xg     = (short*)(w + 8u*1024*1024);
    short* whh_bf = (short*)(w + 9u*1024*1024);
    unsigned* bar = (unsigned*)(w + 11u*1024*1024);
    float* outp   = (float*)d_out;

    conv_whh<<<512, 256, 0, stream>>>(d_in[4], whh_bf, bar);
    build_xg<<<dim3(16, 64), 256, 0, stream>>>(d_in[2], d_in[3], d_in[5], d_in[6], xg);
    lstm_fused<<<256, 512, 0, stream>>>(seq, lens, whh_bf, xg, h_even, h_odd, outp, bar);
}

// Round 13
// 423.969 us; speedup vs baseline: 1.3319x; 1.0219x over previous
//
#include <hip/hip_runtime.h>
#include <hip/hip_bf16.h>

typedef __attribute__((ext_vector_type(8))) short short8;
typedef __attribute__((ext_vector_type(4))) short short4v;
typedef __attribute__((ext_vector_type(4))) float floatx4;

#define EDIM 256
#define HDIM 512
#define LDIM 16
#define NCOL 2048
#define BM 256      // chains per block
#define KC 32       // k-chunk

__device__ __forceinline__ float fsigmoid(float x){ return 1.0f/(1.0f+__expf(-x)); }
__device__ __forceinline__ float ftanh(float x){ return 2.0f/(1.0f+__expf(-2.0f*x))-1.0f; }
__device__ __forceinline__ float bf2f(short s){
    union { unsigned u; float f; } cv; cv.u = ((unsigned)(unsigned short)s) << 16; return cv.f;
}
__device__ __forceinline__ unsigned short f2bf_bits(float v){
    union { __hip_bfloat16 h; unsigned short u; } cv;
    cv.h = __float2bfloat16(v); return cv.u;
}

// 16B coherent load: two agent-scope RELAXED atomic u64 loads (L2-bypass,
// sees write-through h stores from any XCD; compiler-managed waits).
__device__ __forceinline__ short8 aload16(const short* p) {
    union { unsigned long long q[2]; short8 s; } u;
    u.q[0] = __hip_atomic_load((const unsigned long long*)p,
                               __ATOMIC_RELAXED, __HIP_MEMORY_SCOPE_AGENT);
    u.q[1] = __hip_atomic_load((const unsigned long long*)p + 1,
                               __ATOMIC_RELAXED, __HIP_MEMORY_SCOPE_AGENT);
    return u.s;
}
// Coherent bf16 store (write-through; single-copy-atomic 2B store).
__device__ __forceinline__ void astore_bf16(short* p, float v) {
    __hip_atomic_store((unsigned short*)p, f2bf_bits(v),
                       __ATOMIC_RELAXED, __HIP_MEMORY_SCOPE_AGENT);
}
// LDS-only barrier: waves sync WITHOUT draining vmcnt (T4) -> staging
// loads stay in flight across chunk boundaries.
__device__ __forceinline__ void lds_barrier() {
    asm volatile("s_waitcnt lgkmcnt(0)" ::: "memory");
    __builtin_amdgcn_s_barrier();
}

__device__ __forceinline__ bool detect_bf16(const short* p) {
    // fp32 buffers' even shorts are low mantissa bits (~uniform) -> exponent
    // field frequently > 0x7B; true bf16 U(-.05,.05) weights never exceed it.
    bool bf = true;
    for (int i = 0; i < 64; i += 2) {
        int e = (((unsigned short)p[i]) >> 7) & 0xFF;
        if (e > 0x7B) bf = false;
    }
    return bf;
}

// ---------------------------------------------------------------------------
// W_hh -> bf16 (copy if already bf16). Also zeroes the group-barrier
// counters (bar[mt*32], 128 B apart) used by lstm_fused.
// ---------------------------------------------------------------------------
__global__ void conv_whh(const void* __restrict__ whhp, short* __restrict__ whh_o,
                         unsigned* __restrict__ bar) {
    if (blockIdx.x == 0)
        for (int i = threadIdx.x; i < 512; i += 256) bar[i] = 0u;
    bool bf = detect_bf16((const short*)whhp);
    int tid = blockIdx.x * blockDim.x + threadIdx.x;
    int stride = gridDim.x * blockDim.x;
    if (bf) {
        const short* s = (const short*)whhp;
        for (int i = tid; i < NCOL * HDIM; i += stride) whh_o[i] = s[i];
    } else {
        const float* s = (const float*)whhp;
        for (int i = tid; i < NCOL * HDIM; i += stride)
            ((__hip_bfloat16*)whh_o)[i] = __float2bfloat16(s[i]);
    }
}

// ---------------------------------------------------------------------------
// xg[id][j][g] = emb[id] . W_ih[g*512+j] + b_ih + b_hh   (bf16 out)
// Layout is [id][j][4 gates] so the LSTM epilogue gathers one 8B vector.
// ---------------------------------------------------------------------------
__global__ void build_xg(const void* __restrict__ embp, const void* __restrict__ wihp,
                         const void* __restrict__ bihp, const void* __restrict__ bhhp,
                         short* __restrict__ xg)
{
    __shared__ float es[16][EDIM];        // 16 KB
    __shared__ float wsm[32][EDIM + 1];   // 32.1 KB (pad breaks bank conflicts)
    bool bf = detect_bf16((const short*)wihp);
    const int idt = blockIdx.x, ct = blockIdx.y, tt = threadIdx.x;

    if (bf) {
        const __hip_bfloat16* e = (const __hip_bfloat16*)embp;
        const __hip_bfloat16* wv = (const __hip_bfloat16*)wihp;
        for (int p = 0; p < 16; ++p) es[p][tt] = __bfloat162float(e[(idt*16+p)*EDIM + tt]);
        for (int p = 0; p < 32; ++p) wsm[p][tt] = __bfloat162float(wv[(ct*32+p)*EDIM + tt]);
    } else {
        const float* e = (const float*)embp;
        const float* wv = (const float*)wihp;
        for (int p = 0; p < 16; ++p) es[p][tt] = e[(idt*16+p)*EDIM + tt];
        for (int p = 0; p < 32; ++p) wsm[p][tt] = wv[(ct*32+p)*EDIM + tt];
    }
    __syncthreads();

    const int col_l = tt & 31, grp = tt >> 5;   // 8 groups x 2 ids
    const int col = ct * 32 + col_l;            // 0..2047, gate-major
    float bsum = bf ? (__bfloat162float(((const __hip_bfloat16*)bihp)[col]) +
                       __bfloat162float(((const __hip_bfloat16*)bhhp)[col]))
                    : (((const float*)bihp)[col] + ((const float*)bhhp)[col]);
    float a0 = 0.f, a1 = 0.f;
    for (int k = 0; k < EDIM; ++k) {
        float wv = wsm[col_l][k];
        a0 += es[grp*2+0][k] * wv;
        a1 += es[grp*2+1][k] * wv;
    }
    const int jj = col & (HDIM - 1), gsel = col >> 9;
    ((__hip_bfloat16*)xg)[(idt*16 + grp*2 + 0)*NCOL + jj*4 + gsel] = __float2bfloat16(a0 + bsum);
    ((__hip_bfloat16*)xg)[(idt*16 + grp*2 + 1)*NCOL + jj*4 + gsel] = __float2bfloat16(a1 + bsum);
}

// ---------------------------------------------------------------------------
// Fused LSTM, 16-wave edition: champion geometry (256 chains x 32 j per
// block, Bs 128K + As 32K = 160K, grid 256, 1 block/CU) but 1024 threads =
// 16 waves -> 4 waves/SIMD (2x the TLP of the 375us champion). Per-wave
// tile halves (32 chains, 8 MFMA/chunk), so natural VGPR demand ~118 fits
// the 128 cap WITHOUT launch-bounds forcing (r11's spill failure mode).
// All other proven pieces verbatim: T4 lgkmcnt-only chunk barriers,
// distance-2 register staging, coherent-atomic h exchange (zero cache
// maintenance), pure relaxed-counter step barrier, xv prefetch in the
// barrier window.
// ---------------------------------------------------------------------------
__launch_bounds__(1024)
__global__ void lstm_fused(const int* __restrict__ seq, const int* __restrict__ lens,
                           const short* __restrict__ whh,   // bf16 [2048][512]
                           const short* __restrict__ xg,    // bf16 [256][512][4]
                           short* __restrict__ hb0, short* __restrict__ hb1,
                           float* __restrict__ out,         // fp32 [4096][512]
                           unsigned* __restrict__ bar)      // [16*32] padded counters
{
    __shared__ __align__(16) short Bs[128 * 512];   // 128 KB, swizzled
    __shared__ __align__(16) short As[2][BM * KC];  // 32 KB, swizzled

    const int f  = blockIdx.x;
    // XCD swizzle: all 16 jt-blocks of an mt tend to land on one XCD (perf
    // only; correctness is placement-independent).
    const int mt = ((f & 7) << 1) | ((f >> 3) & 1);
    const int jt = f >> 4;
    const int tid = threadIdx.x;
    const int wave = tid >> 6, lane = tid & 63;
    const int q = lane >> 4, ln = lane & 15;
    const int ms = wave & 7, ns = wave >> 3;   // 8 m-subs x 2 n-subs
    const int jloc = ns * 16 + ln;             // 0..31 within block's j-slab
    const int jglob = jt * 32 + jloc;

    // ---- stage W_hh slab into LDS once: rows g*32+jl <- whh[g*512+jt*32+jl]
    // swizzle: elem col c stored at c ^ ((row&7)<<3)  (16B-group XOR)
#pragma unroll
    for (int it = 0; it < 8; ++it) {
        int task = it * 1024 + tid;           // 8192 tasks of 16 B
        int row = task >> 6, seg = task & 63;
        int grow = (row >> 5) * HDIM + jt * 32 + (row & 31);
        short8 v = *(const short8*)(whh + grow * HDIM + seg * 8);
        *(short8*)&Bs[row * 512 + ((seg * 8) ^ ((row & 7) << 3))] = v;
    }

    const int chainbase = mt * BM + ms * 32 + q * 4;
    const int obase = chainbase * HDIM + jglob;
    unsigned* __restrict__ barp = bar + (mt << 5);

    // staging task constants: thread covers ONE row-segment of 16 B
    const int srow = tid >> 2, sseg = tid & 3;           // srow 0..255
    const int g0 = srow * HDIM + sseg * 8;               // global elem offset
    const int l0 = srow * KC + ((sseg * 8) ^ ((srow & 3) << 3));   // LDS

    // packed lens (values 1..16 fit a byte) -> 2 VGPRs; cells e: mf=e>>2 (0..1)
    unsigned lnspk[2] = {0u, 0u};
#pragma unroll
    for (int e = 0; e < 8; ++e)
        lnspk[e >> 2] |= ((unsigned)lens[chainbase + (e >> 2) * 16 + (e & 3)] & 0xFFu)
                         << ((e & 3) * 8);

    float c_st[8], h_st[8];
#pragma unroll
    for (int e = 0; e < 8; ++e) { c_st[e] = 0.f; h_st[e] = 0.f; }

    // prefetch t=0 ids + gate vectors (normal cached loads: read-only data)
    int idsN[8];
    short4v xv[8];
#pragma unroll
    for (int e = 0; e < 8; ++e)
        idsN[e] = seq[(chainbase + (e >> 2) * 16 + (e & 3)) * LDIM + 0];
#pragma unroll
    for (int e = 0; e < 8; ++e)
        xv[e] = *(const short4v*)(xg + idsN[e] * NCOL + jglob * 4);

    for (int t = 0; t < LDIM; ++t) {
        const short* hr = (t & 1) ? hb1 : hb0;   // written at step t-1
        short* hw       = (t & 1) ? hb0 : hb1;
        const bool notlast = (t < LDIM - 1);

        // seq ids for t+1: read-only, issue now, land during the GEMM
        if (notlast) {
#pragma unroll
            for (int e = 0; e < 8; ++e)
                idsN[e] = seq[(chainbase + (e >> 2) * 16 + (e & 3)) * LDIM + t + 1];
        }

        floatx4 acc[4][2];  // [gate][mfrag]
#pragma unroll
        for (int g = 0; g < 4; ++g)
#pragma unroll
            for (int mf = 0; mf < 2; ++mf) acc[g][mf] = (floatx4){0.f, 0.f, 0.f, 0.f};

        if (t > 0) {
            const short* abase = hr + (size_t)mt * BM * HDIM;
            // rq[parity]: distance-2 register staging (one 16B piece/thread)
            short8 rq[2];
            {   // prologue: chunk 0 -> LDS; chunk 1 -> regs
                short8 v0 = aload16(abase + g0);
                rq[1]     = aload16(abase + g0 + KC);
                *(short8*)&As[0][l0] = v0;
            }
            lds_barrier();
#pragma unroll
            for (int kc = 0; kc < 16; ++kc) {
                const int b = kc & 1;
                // ds_write chunk kc+1 (regs loaded 2 chunks ago; vmcnt wait
                // is for exactly these -- latency fully covered)
                if (kc < 15)
                    *(short8*)&As[b ^ 1][l0] = rq[(kc + 1) & 1];
                // issue global load for chunk kc+2 (stays in flight across
                // the vmcnt-free chunk barriers)
                if (kc < 14)
                    rq[kc & 1] = aload16(abase + g0 + (kc + 2) * KC);
                // compute on buffer b
                short8 af[2], bfr[4];
#pragma unroll
                for (int mf = 0; mf < 2; ++mf)
                    af[mf] = *(const short8*)&As[b][(ms * 32 + mf * 16 + ln) * KC +
                                                    ((q * 8) ^ ((ln & 3) << 3))];
#pragma unroll
                for (int g = 0; g < 4; ++g)
                    bfr[g] = *(const short8*)&Bs[(g * 32 + jloc) * 512 +
                                                 ((kc * 32 + q * 8) ^ ((ln & 7) << 3))];
                __builtin_amdgcn_s_setprio(1);
#pragma unroll
                for (int g = 0; g < 4; ++g)
#pragma unroll
                    for (int mf = 0; mf < 2; ++mf)
                        acc[g][mf] = __builtin_amdgcn_mfma_f32_16x16x32_bf16(
                            af[mf], bfr[g], acc[g][mf], 0, 0, 0);
                __builtin_amdgcn_s_setprio(0);
                lds_barrier();   // LDS-only: global loads NOT drained (T4)
            }
        }

        // ---- epilogue: prefetched xg + cell update. C/D: col=ln, row=q*4+r
#pragma unroll
        for (int e = 0; e < 8; ++e) {
            const int mf = e >> 2, r = e & 3;
            float p0 = acc[0][mf][r] + bf2f(xv[e][0]);
            float p1 = acc[1][mf][r] + bf2f(xv[e][1]);
            float p2 = acc[2][mf][r] + bf2f(xv[e][2]);
            float p3 = acc[3][mf][r] + bf2f(xv[e][3]);
            float ig = fsigmoid(p0);
            float fg = fsigmoid(p1);
            float gg = ftanh(p2);
            float og = fsigmoid(p3);
            float cn = fg * c_st[e] + ig * gg;
            float hn = og * ftanh(cn);
            bool mk = (int)((lnspk[e >> 2] >> ((e & 3) * 8)) & 0xFFu) > t;
            float hsv = mk ? hn : h_st[e];
            float csv = mk ? cn : c_st[e];
            h_st[e] = hsv; c_st[e] = csv;
            int off = obase + (mf * 16 + r) * HDIM;
            if (notlast) astore_bf16(hw + off, hsv);   // coherent write-through
            else         out[off] = hsv;               // final h, fp32
        }

        // ---- step barrier among the 16 jt-blocks of this mt: pure relaxed
        // counter, zero cache ops. __syncthreads drains vmcnt -> all h
        // atomic stores are globally visible (write-through) before arrive.
        if (notlast) {
            __syncthreads();
#pragma unroll
            for (int e = 0; e < 8; ++e)      // xg for t+1 (read-only, cached)
                xv[e] = *(const short4v*)(xg + idsN[e] * NCOL + jglob * 4);
            if (tid == 0) {
                __hip_atomic_fetch_add(barp, 1u, __ATOMIC_RELAXED,
                                       __HIP_MEMORY_SCOPE_AGENT);
                const unsigned target = 16u * (unsigned)(t + 1);
                while (__hip_atomic_load(barp, __ATOMIC_RELAXED,
                                         __HIP_MEMORY_SCOPE_AGENT) < target)
                    __builtin_amdgcn_s_sleep(2);
            }
            __syncthreads();
        }
    }
}

extern "C" void kernel_launch(void* const* d_in, const int* in_sizes, int n_in,
                              void* d_out, int out_size, void* d_ws, size_t ws_size,
                              hipStream_t stream) {
    const int* seq  = (const int*)d_in[0];
    const int* lens = (const int*)d_in[1];

    // ws: h_even 4M | h_odd 4M | xg 1M | whh_bf 2M | bar 2KB (<= proven 11.14M)
    char* w = (char*)d_ws;
    short* h_even = (short*)w;
    short* h_odd  = (short*)(w + 4u*1024*1024);
    short* xg     = (short*)(w + 8u*1024*1024);
    short* whh_bf = (short*)(w + 9u*1024*1024);
    unsigned* bar = (unsigned*)(w + 11u*1024*1024);
    float* outp   = (float*)d_out;

    conv_whh<<<512, 256, 0, stream>>>(d_in[4], whh_bf, bar);
    build_xg<<<dim3(16, 64), 256, 0, stream>>>(d_in[2], d_in[3], d_in[5], d_in[6], xg);
    lstm_fused<<<256, 1024, 0, stream>>>(seq, lens, whh_bf, xg, h_even, h_odd, outp, bar);
}

// Round 14
// 420.560 us; speedup vs baseline: 1.3427x; 1.0081x over previous
//
#include <hip/hip_runtime.h>
#include <hip/hip_bf16.h>

typedef __attribute__((ext_vector_type(8))) short short8;
typedef __attribute__((ext_vector_type(4))) short short4v;
typedef __attribute__((ext_vector_type(4))) float floatx4;

#define EDIM 256
#define HDIM 512
#define LDIM 16
#define NCOL 2048
#define BM 256      // chains per block
#define KC 32       // k-chunk

__device__ __forceinline__ float fsigmoid(float x){ return 1.0f/(1.0f+__expf(-x)); }
__device__ __forceinline__ float ftanh(float x){ return 2.0f/(1.0f+__expf(-2.0f*x))-1.0f; }
__device__ __forceinline__ float bf2f(short s){
    union { unsigned u; float f; } cv; cv.u = ((unsigned)(unsigned short)s) << 16; return cv.f;
}
__device__ __forceinline__ unsigned short f2bf_bits(float v){
    union { __hip_bfloat16 h; unsigned short u; } cv;
    cv.h = __float2bfloat16(v); return cv.u;
}

// 16B coherent load: two agent-scope RELAXED atomic u64 loads (L2-bypass,
// sees write-through h stores from any XCD; compiler-managed waits).
__device__ __forceinline__ short8 aload16(const short* p) {
    union { unsigned long long q[2]; short8 s; } u;
    u.q[0] = __hip_atomic_load((const unsigned long long*)p,
                               __ATOMIC_RELAXED, __HIP_MEMORY_SCOPE_AGENT);
    u.q[1] = __hip_atomic_load((const unsigned long long*)p + 1,
                               __ATOMIC_RELAXED, __HIP_MEMORY_SCOPE_AGENT);
    return u.s;
}
// Coherent bf16 store (write-through; single-copy-atomic 2B store).
__device__ __forceinline__ void astore_bf16(short* p, float v) {
    __hip_atomic_store((unsigned short*)p, f2bf_bits(v),
                       __ATOMIC_RELAXED, __HIP_MEMORY_SCOPE_AGENT);
}
// LDS-only barrier: waves sync WITHOUT draining vmcnt (T4) -> staging
// loads stay in flight across chunk boundaries.
__device__ __forceinline__ void lds_barrier() {
    asm volatile("s_waitcnt lgkmcnt(0)" ::: "memory");
    __builtin_amdgcn_s_barrier();
}

__device__ __forceinline__ bool detect_bf16(const short* p) {
    // fp32 buffers' even shorts are low mantissa bits (~uniform) -> exponent
    // field frequently > 0x7B; true bf16 U(-.05,.05) weights never exceed it.
    bool bf = true;
    for (int i = 0; i < 64; i += 2) {
        int e = (((unsigned short)p[i]) >> 7) & 0xFF;
        if (e > 0x7B) bf = false;
    }
    return bf;
}

// ---------------------------------------------------------------------------
// W_hh -> bf16 (copy if already bf16). Also zeroes the group-barrier
// counters (bar[mt*32], 128 B apart) used by lstm_fused.
// ---------------------------------------------------------------------------
__global__ void conv_whh(const void* __restrict__ whhp, short* __restrict__ whh_o,
                         unsigned* __restrict__ bar) {
    if (blockIdx.x == 0)
        for (int i = threadIdx.x; i < 512; i += 256) bar[i] = 0u;
    bool bf = detect_bf16((const short*)whhp);
    int tid = blockIdx.x * blockDim.x + threadIdx.x;
    int stride = gridDim.x * blockDim.x;
    if (bf) {
        const short* s = (const short*)whhp;
        for (int i = tid; i < NCOL * HDIM; i += stride) whh_o[i] = s[i];
    } else {
        const float* s = (const float*)whhp;
        for (int i = tid; i < NCOL * HDIM; i += stride)
            ((__hip_bfloat16*)whh_o)[i] = __float2bfloat16(s[i]);
    }
}

// ---------------------------------------------------------------------------
// xg[id][j][g] = emb[id] . W_ih[g*512+j] + b_ih + b_hh   (bf16 out)
// Layout is [id][j][4 gates] so the LSTM epilogue gathers one 8B vector.
// ---------------------------------------------------------------------------
__global__ void build_xg(const void* __restrict__ embp, const void* __restrict__ wihp,
                         const void* __restrict__ bihp, const void* __restrict__ bhhp,
                         short* __restrict__ xg)
{
    __shared__ float es[16][EDIM];        // 16 KB
    __shared__ float wsm[32][EDIM + 1];   // 32.1 KB (pad breaks bank conflicts)
    bool bf = detect_bf16((const short*)wihp);
    const int idt = blockIdx.x, ct = blockIdx.y, tt = threadIdx.x;

    if (bf) {
        const __hip_bfloat16* e = (const __hip_bfloat16*)embp;
        const __hip_bfloat16* wv = (const __hip_bfloat16*)wihp;
        for (int p = 0; p < 16; ++p) es[p][tt] = __bfloat162float(e[(idt*16+p)*EDIM + tt]);
        for (int p = 0; p < 32; ++p) wsm[p][tt] = __bfloat162float(wv[(ct*32+p)*EDIM + tt]);
    } else {
        const float* e = (const float*)embp;
        const float* wv = (const float*)wihp;
        for (int p = 0; p < 16; ++p) es[p][tt] = e[(idt*16+p)*EDIM + tt];
        for (int p = 0; p < 32; ++p) wsm[p][tt] = wv[(ct*32+p)*EDIM + tt];
    }
    __syncthreads();

    const int col_l = tt & 31, grp = tt >> 5;   // 8 groups x 2 ids
    const int col = ct * 32 + col_l;            // 0..2047, gate-major
    float bsum = bf ? (__bfloat162float(((const __hip_bfloat16*)bihp)[col]) +
                       __bfloat162float(((const __hip_bfloat16*)bhhp)[col]))
                    : (((const float*)bihp)[col] + ((const float*)bhhp)[col]);
    float a0 = 0.f, a1 = 0.f;
    for (int k = 0; k < EDIM; ++k) {
        float wv = wsm[col_l][k];
        a0 += es[grp*2+0][k] * wv;
        a1 += es[grp*2+1][k] * wv;
    }
    const int jj = col & (HDIM - 1), gsel = col >> 9;
    ((__hip_bfloat16*)xg)[(idt*16 + grp*2 + 0)*NCOL + jj*4 + gsel] = __float2bfloat16(a0 + bsum);
    ((__hip_bfloat16*)xg)[(idt*16 + grp*2 + 1)*NCOL + jj*4 + gsel] = __float2bfloat16(a1 + bsum);
}

// ---------------------------------------------------------------------------
// Fused LSTM, 16-wave edition with a PROPER register budget:
// __launch_bounds__(1024, 4): 16 waves/block / 4 SIMDs = 4 waves/EU ->
// VGPR cap 128 (vs r13's compiler-chosen 64, which spilled ~300 MB/dispatch
// of scratch traffic to HBM -- FETCH 318 MB, WRITE 226 MB, one 31.7 ms
// outlier). Natural demand ~110 fits 128 with zero spills.
// Geometry (r13): 256 chains x 32 j per block, Bs 128K + As 32K = 160K LDS,
// grid 256, 1 block/CU, 16 waves = 4/SIMD (2x champion TLP). Proven pieces
// verbatim: T4 lgkmcnt-only chunk barriers, distance-2 register staging,
// coherent-atomic h exchange (zero cache maintenance), relaxed-counter step
// barrier, xv prefetch in the barrier window.
// ---------------------------------------------------------------------------
__launch_bounds__(1024, 4)
__global__ void lstm_fused(const int* __restrict__ seq, const int* __restrict__ lens,
                           const short* __restrict__ whh,   // bf16 [2048][512]
                           const short* __restrict__ xg,    // bf16 [256][512][4]
                           short* __restrict__ hb0, short* __restrict__ hb1,
                           float* __restrict__ out,         // fp32 [4096][512]
                           unsigned* __restrict__ bar)      // [16*32] padded counters
{
    __shared__ __align__(16) short Bs[128 * 512];   // 128 KB, swizzled
    __shared__ __align__(16) short As[2][BM * KC];  // 32 KB, swizzled

    const int f  = blockIdx.x;
    // XCD swizzle: all 16 jt-blocks of an mt tend to land on one XCD (perf
    // only; correctness is placement-independent).
    const int mt = ((f & 7) << 1) | ((f >> 3) & 1);
    const int jt = f >> 4;
    const int tid = threadIdx.x;
    const int wave = tid >> 6, lane = tid & 63;
    const int q = lane >> 4, ln = lane & 15;
    const int ms = wave & 7, ns = wave >> 3;   // 8 m-subs x 2 n-subs
    const int jloc = ns * 16 + ln;             // 0..31 within block's j-slab
    const int jglob = jt * 32 + jloc;

    // ---- stage W_hh slab into LDS once: rows g*32+jl <- whh[g*512+jt*32+jl]
    // swizzle: elem col c stored at c ^ ((row&7)<<3)  (16B-group XOR)
#pragma unroll
    for (int it = 0; it < 8; ++it) {
        int task = it * 1024 + tid;           // 8192 tasks of 16 B
        int row = task >> 6, seg = task & 63;
        int grow = (row >> 5) * HDIM + jt * 32 + (row & 31);
        short8 v = *(const short8*)(whh + grow * HDIM + seg * 8);
        *(short8*)&Bs[row * 512 + ((seg * 8) ^ ((row & 7) << 3))] = v;
    }

    const int chainbase = mt * BM + ms * 32 + q * 4;
    const int obase = chainbase * HDIM + jglob;
    unsigned* __restrict__ barp = bar + (mt << 5);

    // staging task constants: thread covers ONE row-segment of 16 B
    const int srow = tid >> 2, sseg = tid & 3;           // srow 0..255
    const int g0 = srow * HDIM + sseg * 8;               // global elem offset
    const int l0 = srow * KC + ((sseg * 8) ^ ((srow & 3) << 3));   // LDS

    // packed lens (values 1..16 fit a byte) -> 2 VGPRs; cells e: mf=e>>2 (0..1)
    unsigned lnspk[2] = {0u, 0u};
#pragma unroll
    for (int e = 0; e < 8; ++e)
        lnspk[e >> 2] |= ((unsigned)lens[chainbase + (e >> 2) * 16 + (e & 3)] & 0xFFu)
                         << ((e & 3) * 8);

    float c_st[8], h_st[8];
#pragma unroll
    for (int e = 0; e < 8; ++e) { c_st[e] = 0.f; h_st[e] = 0.f; }

    // prefetch t=0 ids + gate vectors (normal cached loads: read-only data)
    int idsN[8];
    short4v xv[8];
#pragma unroll
    for (int e = 0; e < 8; ++e)
        idsN[e] = seq[(chainbase + (e >> 2) * 16 + (e & 3)) * LDIM + 0];
#pragma unroll
    for (int e = 0; e < 8; ++e)
        xv[e] = *(const short4v*)(xg + idsN[e] * NCOL + jglob * 4);

    for (int t = 0; t < LDIM; ++t) {
        const short* hr = (t & 1) ? hb1 : hb0;   // written at step t-1
        short* hw       = (t & 1) ? hb0 : hb1;
        const bool notlast = (t < LDIM - 1);

        // seq ids for t+1: read-only, issue now, land during the GEMM
        if (notlast) {
#pragma unroll
            for (int e = 0; e < 8; ++e)
                idsN[e] = seq[(chainbase + (e >> 2) * 16 + (e & 3)) * LDIM + t + 1];
        }

        floatx4 acc[4][2];  // [gate][mfrag]
#pragma unroll
        for (int g = 0; g < 4; ++g)
#pragma unroll
            for (int mf = 0; mf < 2; ++mf) acc[g][mf] = (floatx4){0.f, 0.f, 0.f, 0.f};

        if (t > 0) {
            const short* abase = hr + (size_t)mt * BM * HDIM;
            // rq[parity]: distance-2 register staging (one 16B piece/thread)
            short8 rq[2];
            {   // prologue: chunk 0 -> LDS; chunk 1 -> regs
                short8 v0 = aload16(abase + g0);
                rq[1]     = aload16(abase + g0 + KC);
                *(short8*)&As[0][l0] = v0;
            }
            lds_barrier();
#pragma unroll
            for (int kc = 0; kc < 16; ++kc) {
                const int b = kc & 1;
                // ds_write chunk kc+1 (regs loaded 2 chunks ago; vmcnt wait
                // is for exactly these -- latency fully covered)
                if (kc < 15)
                    *(short8*)&As[b ^ 1][l0] = rq[(kc + 1) & 1];
                // issue global load for chunk kc+2 (stays in flight across
                // the vmcnt-free chunk barriers)
                if (kc < 14)
                    rq[kc & 1] = aload16(abase + g0 + (kc + 2) * KC);
                // compute on buffer b
                short8 af[2], bfr[4];
#pragma unroll
                for (int mf = 0; mf < 2; ++mf)
                    af[mf] = *(const short8*)&As[b][(ms * 32 + mf * 16 + ln) * KC +
                                                    ((q * 8) ^ ((ln & 3) << 3))];
#pragma unroll
                for (int g = 0; g < 4; ++g)
                    bfr[g] = *(const short8*)&Bs[(g * 32 + jloc) * 512 +
                                                 ((kc * 32 + q * 8) ^ ((ln & 7) << 3))];
                __builtin_amdgcn_s_setprio(1);
#pragma unroll
                for (int g = 0; g < 4; ++g)
#pragma unroll
                    for (int mf = 0; mf < 2; ++mf)
                        acc[g][mf] = __builtin_amdgcn_mfma_f32_16x16x32_bf16(
                            af[mf], bfr[g], acc[g][mf], 0, 0, 0);
                __builtin_amdgcn_s_setprio(0);
                lds_barrier();   // LDS-only: global loads NOT drained (T4)
            }
        }

        // ---- epilogue: prefetched xg + cell update. C/D: col=ln, row=q*4+r
#pragma unroll
        for (int e = 0; e < 8; ++e) {
            const int mf = e >> 2, r = e & 3;
            float p0 = acc[0][mf][r] + bf2f(xv[e][0]);
            float p1 = acc[1][mf][r] + bf2f(xv[e][1]);
            float p2 = acc[2][mf][r] + bf2f(xv[e][2]);
            float p3 = acc[3][mf][r] + bf2f(xv[e][3]);
            float ig = fsigmoid(p0);
            float fg = fsigmoid(p1);
            float gg = ftanh(p2);
            float og = fsigmoid(p3);
            float cn = fg * c_st[e] + ig * gg;
            float hn = og * ftanh(cn);
            bool mk = (int)((lnspk[e >> 2] >> ((e & 3) * 8)) & 0xFFu) > t;
            float hsv = mk ? hn : h_st[e];
            float csv = mk ? cn : c_st[e];
            h_st[e] = hsv; c_st[e] = csv;
            int off = obase + (mf * 16 + r) * HDIM;
            if (notlast) astore_bf16(hw + off, hsv);   // coherent write-through
            else         out[off] = hsv;               // final h, fp32
        }

        // ---- step barrier among the 16 jt-blocks of this mt: pure relaxed
        // counter, zero cache ops. __syncthreads drains vmcnt -> all h
        // atomic stores are globally visible (write-through) before arrive.
        if (notlast) {
            __syncthreads();
#pragma unroll
            for (int e = 0; e < 8; ++e)      // xg for t+1 (read-only, cached)
                xv[e] = *(const short4v*)(xg + idsN[e] * NCOL + jglob * 4);
            if (tid == 0) {
                __hip_atomic_fetch_add(barp, 1u, __ATOMIC_RELAXED,
                                       __HIP_MEMORY_SCOPE_AGENT);
                const unsigned target = 16u * (unsigned)(t + 1);
                while (__hip_atomic_load(barp, __ATOMIC_RELAXED,
                                         __HIP_MEMORY_SCOPE_AGENT) < target)
                    __builtin_amdgcn_s_sleep(2);
            }
            __syncthreads();
        }
    }
}

extern "C" void kernel_launch(void* const* d_in, const int* in_sizes, int n_in,
                              void* d_out, int out_size, void* d_ws, size_t ws_size,
                              hipStream_t stream) {
    const int* seq  = (const int*)d_in[0];
    const int* lens = (const int*)d_in[1];

    // ws: h_even 4M | h_odd 4M | xg 1M | whh_bf 2M | bar 2KB (<= proven 11.14M)
    char* w = (char*)d_ws;
    short* h_even = (short*)w;
    short* h_odd  = (short*)(w + 4u*1024*1024);
    short* xg     = (short*)(w + 8u*1024*1024);
    short* whh_bf = (short*)(w + 9u*1024*1024);
    unsigned* bar = (unsigned*)(w + 11u*1024*1024);
    float* outp   = (float*)d_out;

    conv_whh<<<512, 256, 0, stream>>>(d_in[4], whh_bf, bar);
    build_xg<<<dim3(16, 64), 256, 0, stream>>>(d_in[2], d_in[3], d_in[5], d_in[6], xg);
    lstm_fused<<<256, 1024, 0, stream>>>(seq, lens, whh_bf, xg, h_even, h_odd, outp, bar);
}

// Round 15
// 346.924 us; speedup vs baseline: 1.6277x; 1.2123x over previous
//
#include <hip/hip_runtime.h>
#include <hip/hip_bf16.h>

typedef __attribute__((ext_vector_type(8))) short short8;
typedef __attribute__((ext_vector_type(4))) short short4v;
typedef __attribute__((ext_vector_type(4))) float floatx4;

#define EDIM 256
#define HDIM 512
#define LDIM 16
#define NCOL 2048
#define BM 256      // chains per block
#define KC 32       // k-chunk

__device__ __forceinline__ float fsigmoid(float x){ return 1.0f/(1.0f+__expf(-x)); }
__device__ __forceinline__ float ftanh(float x){ return 2.0f/(1.0f+__expf(-2.0f*x))-1.0f; }
__device__ __forceinline__ float bf2f(short s){
    union { unsigned u; float f; } cv; cv.u = ((unsigned)(unsigned short)s) << 16; return cv.f;
}
__device__ __forceinline__ unsigned short f2bf_bits(float v){
    union { __hip_bfloat16 h; unsigned short u; } cv;
    cv.h = __float2bfloat16(v); return cv.u;
}

// 16B coherent load: two agent-scope RELAXED atomic u64 loads (L2-bypass,
// sees write-through h stores from any XCD; compiler-managed waits).
__device__ __forceinline__ short8 aload16(const short* p) {
    union { unsigned long long q[2]; short8 s; } u;
    u.q[0] = __hip_atomic_load((const unsigned long long*)p,
                               __ATOMIC_RELAXED, __HIP_MEMORY_SCOPE_AGENT);
    u.q[1] = __hip_atomic_load((const unsigned long long*)p + 1,
                               __ATOMIC_RELAXED, __HIP_MEMORY_SCOPE_AGENT);
    return u.s;
}
// Coherent 2B load (h_old readback; write-through value from step t-1).
__device__ __forceinline__ unsigned short aload2(const short* p) {
    return __hip_atomic_load((const unsigned short*)p,
                             __ATOMIC_RELAXED, __HIP_MEMORY_SCOPE_AGENT);
}
// Coherent bf16 store (write-through; single-copy-atomic 2B store).
__device__ __forceinline__ void astore_bf16(short* p, float v) {
    __hip_atomic_store((unsigned short*)p, f2bf_bits(v),
                       __ATOMIC_RELAXED, __HIP_MEMORY_SCOPE_AGENT);
}
// LDS-only barrier: waves sync WITHOUT draining vmcnt (T4) -> staging
// loads stay in flight across chunk boundaries.
__device__ __forceinline__ void lds_barrier() {
    asm volatile("s_waitcnt lgkmcnt(0)" ::: "memory");
    __builtin_amdgcn_s_barrier();
}

__device__ __forceinline__ bool detect_bf16(const short* p) {
    // fp32 buffers' even shorts are low mantissa bits (~uniform) -> exponent
    // field frequently > 0x7B; true bf16 U(-.05,.05) weights never exceed it.
    bool bf = true;
    for (int i = 0; i < 64; i += 2) {
        int e = (((unsigned short)p[i]) >> 7) & 0xFF;
        if (e > 0x7B) bf = false;
    }
    return bf;
}

// ---------------------------------------------------------------------------
// W_hh -> bf16 (copy if already bf16). Also zeroes the group-barrier
// counters (bar[mt*32], 128 B apart) used by lstm_fused.
// ---------------------------------------------------------------------------
__global__ void conv_whh(const void* __restrict__ whhp, short* __restrict__ whh_o,
                         unsigned* __restrict__ bar) {
    if (blockIdx.x == 0)
        for (int i = threadIdx.x; i < 512; i += 256) bar[i] = 0u;
    bool bf = detect_bf16((const short*)whhp);
    int tid = blockIdx.x * blockDim.x + threadIdx.x;
    int stride = gridDim.x * blockDim.x;
    if (bf) {
        const short* s = (const short*)whhp;
        for (int i = tid; i < NCOL * HDIM; i += stride) whh_o[i] = s[i];
    } else {
        const float* s = (const float*)whhp;
        for (int i = tid; i < NCOL * HDIM; i += stride)
            ((__hip_bfloat16*)whh_o)[i] = __float2bfloat16(s[i]);
    }
}

// ---------------------------------------------------------------------------
// xg[id][j][g] = emb[id] . W_ih[g*512+j] + b_ih + b_hh   (bf16 out)
// Layout is [id][j][4 gates] so the LSTM epilogue gathers one 8B vector.
// ---------------------------------------------------------------------------
__global__ void build_xg(const void* __restrict__ embp, const void* __restrict__ wihp,
                         const void* __restrict__ bihp, const void* __restrict__ bhhp,
                         short* __restrict__ xg)
{
    __shared__ float es[16][EDIM];        // 16 KB
    __shared__ float wsm[32][EDIM + 1];   // 32.1 KB (pad breaks bank conflicts)
    bool bf = detect_bf16((const short*)wihp);
    const int idt = blockIdx.x, ct = blockIdx.y, tt = threadIdx.x;

    if (bf) {
        const __hip_bfloat16* e = (const __hip_bfloat16*)embp;
        const __hip_bfloat16* wv = (const __hip_bfloat16*)wihp;
        for (int p = 0; p < 16; ++p) es[p][tt] = __bfloat162float(e[(idt*16+p)*EDIM + tt]);
        for (int p = 0; p < 32; ++p) wsm[p][tt] = __bfloat162float(wv[(ct*32+p)*EDIM + tt]);
    } else {
        const float* e = (const float*)embp;
        const float* wv = (const float*)wihp;
        for (int p = 0; p < 16; ++p) es[p][tt] = e[(idt*16+p)*EDIM + tt];
        for (int p = 0; p < 32; ++p) wsm[p][tt] = wv[(ct*32+p)*EDIM + tt];
    }
    __syncthreads();

    const int col_l = tt & 31, grp = tt >> 5;   // 8 groups x 2 ids
    const int col = ct * 32 + col_l;            // 0..2047, gate-major
    float bsum = bf ? (__bfloat162float(((const __hip_bfloat16*)bihp)[col]) +
                       __bfloat162float(((const __hip_bfloat16*)bhhp)[col]))
                    : (((const float*)bihp)[col] + ((const float*)bhhp)[col]);
    float a0 = 0.f, a1 = 0.f;
    for (int k = 0; k < EDIM; ++k) {
        float wv = wsm[col_l][k];
        a0 += es[grp*2+0][k] * wv;
        a1 += es[grp*2+1][k] * wv;
    }
    const int jj = col & (HDIM - 1), gsel = col >> 9;
    ((__hip_bfloat16*)xg)[(idt*16 + grp*2 + 0)*NCOL + jj*4 + gsel] = __float2bfloat16(a0 + bsum);
    ((__hip_bfloat16*)xg)[(idt*16 + grp*2 + 1)*NCOL + jj*4 + gsel] = __float2bfloat16(a1 + bsum);
}

// ---------------------------------------------------------------------------
// Fused LSTM, 16-wave LOW-PRESSURE edition. r13/r14 proved 4 waves/SIMD
// helps but spilled: a 1024-thread workgroup hard-caps 128 regs/wave,
// split ~64 ArchVGPR + 64 AGPR, and the prefetch state (xv 16 + idsN 8 +
// h_st 8 VGPRs) carried across the k-loop blew the 64 -> ~300 MB/dispatch
// scratch traffic. Fix: load-on-use epilogue --
//   * ids + xg gate-vectors loaded inline in the epilogue (read-only,
//     L2/L3-warm; the spill-reloads were doing these trips anyway),
//   * h_old re-read from hr (1 coherent 2B load; hr holds the blended h
//     of t-1 for every chain; at t=0 mask is always true so value unused).
// Persistent state ~20 VGPR, k-loop peak ~58, epilogue peak ~60: fits 64.
// Geometry + all proven pieces r14-verbatim.
// ---------------------------------------------------------------------------
__launch_bounds__(1024, 4)
__global__ void lstm_fused(const int* __restrict__ seq, const int* __restrict__ lens,
                           const short* __restrict__ whh,   // bf16 [2048][512]
                           const short* __restrict__ xg,    // bf16 [256][512][4]
                           short* __restrict__ hb0, short* __restrict__ hb1,
                           float* __restrict__ out,         // fp32 [4096][512]
                           unsigned* __restrict__ bar)      // [16*32] padded counters
{
    __shared__ __align__(16) short Bs[128 * 512];   // 128 KB, swizzled
    __shared__ __align__(16) short As[2][BM * KC];  // 32 KB, swizzled

    const int f  = blockIdx.x;
    // XCD swizzle: all 16 jt-blocks of an mt tend to land on one XCD (perf
    // only; correctness is placement-independent).
    const int mt = ((f & 7) << 1) | ((f >> 3) & 1);
    const int jt = f >> 4;
    const int tid = threadIdx.x;
    const int wave = tid >> 6, lane = tid & 63;
    const int q = lane >> 4, ln = lane & 15;
    const int ms = wave & 7, ns = wave >> 3;   // 8 m-subs x 2 n-subs
    const int jloc = ns * 16 + ln;             // 0..31 within block's j-slab
    const int jglob = jt * 32 + jloc;

    // ---- stage W_hh slab into LDS once: rows g*32+jl <- whh[g*512+jt*32+jl]
    // swizzle: elem col c stored at c ^ ((row&7)<<3)  (16B-group XOR)
#pragma unroll
    for (int it = 0; it < 8; ++it) {
        int task = it * 1024 + tid;           // 8192 tasks of 16 B
        int row = task >> 6, seg = task & 63;
        int grow = (row >> 5) * HDIM + jt * 32 + (row & 31);
        short8 v = *(const short8*)(whh + grow * HDIM + seg * 8);
        *(short8*)&Bs[row * 512 + ((seg * 8) ^ ((row & 7) << 3))] = v;
    }

    const int chainbase = mt * BM + ms * 32 + q * 4;
    const int obase = chainbase * HDIM + jglob;
    unsigned* __restrict__ barp = bar + (mt << 5);

    // staging task constants: thread covers ONE row-segment of 16 B
    const int srow = tid >> 2, sseg = tid & 3;           // srow 0..255
    const int g0 = srow * HDIM + sseg * 8;               // global elem offset
    const int l0 = srow * KC + ((sseg * 8) ^ ((srow & 3) << 3));   // LDS

    // packed lens (values 1..16 fit a byte) -> 2 VGPRs; cells e: mf=e>>2 (0..1)
    unsigned lnspk[2] = {0u, 0u};
#pragma unroll
    for (int e = 0; e < 8; ++e)
        lnspk[e >> 2] |= ((unsigned)lens[chainbase + (e >> 2) * 16 + (e & 3)] & 0xFFu)
                         << ((e & 3) * 8);

    float c_st[8];
#pragma unroll
    for (int e = 0; e < 8; ++e) c_st[e] = 0.f;

    for (int t = 0; t < LDIM; ++t) {
        const short* hr = (t & 1) ? hb1 : hb0;   // written at step t-1
        short* hw       = (t & 1) ? hb0 : hb1;
        const bool notlast = (t < LDIM - 1);

        floatx4 acc[4][2];  // [gate][mfrag] -- lives in the AGPR half
#pragma unroll
        for (int g = 0; g < 4; ++g)
#pragma unroll
            for (int mf = 0; mf < 2; ++mf) acc[g][mf] = (floatx4){0.f, 0.f, 0.f, 0.f};

        if (t > 0) {
            const short* abase = hr + (size_t)mt * BM * HDIM;
            // rq[parity]: distance-2 register staging (one 16B piece/thread)
            short8 rq[2];
            {   // prologue: chunk 0 -> LDS; chunk 1 -> regs
                short8 v0 = aload16(abase + g0);
                rq[1]     = aload16(abase + g0 + KC);
                *(short8*)&As[0][l0] = v0;
            }
            lds_barrier();
#pragma unroll
            for (int kc = 0; kc < 16; ++kc) {
                const int b = kc & 1;
                // ds_write chunk kc+1 (regs loaded 2 chunks ago; vmcnt wait
                // is for exactly these -- latency fully covered)
                if (kc < 15)
                    *(short8*)&As[b ^ 1][l0] = rq[(kc + 1) & 1];
                // issue global load for chunk kc+2 (stays in flight across
                // the vmcnt-free chunk barriers)
                if (kc < 14)
                    rq[kc & 1] = aload16(abase + g0 + (kc + 2) * KC);
                // compute on buffer b
                short8 af[2], bfr[4];
#pragma unroll
                for (int mf = 0; mf < 2; ++mf)
                    af[mf] = *(const short8*)&As[b][(ms * 32 + mf * 16 + ln) * KC +
                                                    ((q * 8) ^ ((ln & 3) << 3))];
#pragma unroll
                for (int g = 0; g < 4; ++g)
                    bfr[g] = *(const short8*)&Bs[(g * 32 + jloc) * 512 +
                                                 ((kc * 32 + q * 8) ^ ((ln & 7) << 3))];
                __builtin_amdgcn_s_setprio(1);
#pragma unroll
                for (int g = 0; g < 4; ++g)
#pragma unroll
                    for (int mf = 0; mf < 2; ++mf)
                        acc[g][mf] = __builtin_amdgcn_mfma_f32_16x16x32_bf16(
                            af[mf], bfr[g], acc[g][mf], 0, 0, 0);
                __builtin_amdgcn_s_setprio(0);
                lds_barrier();   // LDS-only: global loads NOT drained (T4)
            }
        }

        // ---- epilogue: LOAD-ON-USE (no cross-k-loop prefetch registers).
        // ids -> xg vectors -> h_old, all L2/L3-warm; issued as three
        // batched bursts so latency overlaps within the epilogue.
        int ids_[8];
#pragma unroll
        for (int e = 0; e < 8; ++e)
            ids_[e] = seq[(chainbase + (e >> 2) * 16 + (e & 3)) * LDIM + t];
        short4v xv_[8];
#pragma unroll
        for (int e = 0; e < 8; ++e)
            xv_[e] = *(const short4v*)(xg + ids_[e] * NCOL + jglob * 4);
        unsigned short hob[8];
        if (t > 0) {
#pragma unroll
            for (int e = 0; e < 8; ++e)
                hob[e] = aload2(hr + obase + ((e >> 2) * 16 + (e & 3)) * HDIM);
        } else {
#pragma unroll
            for (int e = 0; e < 8; ++e) hob[e] = 0;
        }
#pragma unroll
        for (int e = 0; e < 8; ++e) {
            const int mf = e >> 2, r = e & 3;
            float p0 = acc[0][mf][r] + bf2f(xv_[e][0]);
            float p1 = acc[1][mf][r] + bf2f(xv_[e][1]);
            float p2 = acc[2][mf][r] + bf2f(xv_[e][2]);
            float p3 = acc[3][mf][r] + bf2f(xv_[e][3]);
            float ig = fsigmoid(p0);
            float fg = fsigmoid(p1);
            float gg = ftanh(p2);
            float og = fsigmoid(p3);
            float hold = bf2f((short)hob[e]);      // blended h at t-1
            float cn = fg * c_st[e] + ig * gg;
            float hn = og * ftanh(cn);
            bool mk = (int)((lnspk[e >> 2] >> ((e & 3) * 8)) & 0xFFu) > t;
            float hsv = mk ? hn : hold;
            float csv = mk ? cn : c_st[e];
            c_st[e] = csv;
            int off = obase + (mf * 16 + r) * HDIM;
            if (notlast) astore_bf16(hw + off, hsv);   // coherent write-through
            else         out[off] = hsv;               // final h, fp32
        }

        // ---- step barrier among the 16 jt-blocks of this mt: pure relaxed
        // counter, zero cache ops. __syncthreads drains vmcnt -> all h
        // atomic stores are globally visible (write-through) before arrive.
        if (notlast) {
            __syncthreads();
            if (tid == 0) {
                __hip_atomic_fetch_add(barp, 1u, __ATOMIC_RELAXED,
                                       __HIP_MEMORY_SCOPE_AGENT);
                const unsigned target = 16u * (unsigned)(t + 1);
                while (__hip_atomic_load(barp, __ATOMIC_RELAXED,
                                         __HIP_MEMORY_SCOPE_AGENT) < target)
                    __builtin_amdgcn_s_sleep(2);
            }
            __syncthreads();
        }
    }
}

extern "C" void kernel_launch(void* const* d_in, const int* in_sizes, int n_in,
                              void* d_out, int out_size, void* d_ws, size_t ws_size,
                              hipStream_t stream) {
    const int* seq  = (const int*)d_in[0];
    const int* lens = (const int*)d_in[1];

    // ws: h_even 4M | h_odd 4M | xg 1M | whh_bf 2M | bar 2KB (<= proven 11.14M)
    char* w = (char*)d_ws;
    short* h_even = (short*)w;
    short* h_odd  = (short*)(w + 4u*1024*1024);
    short* xg     = (short*)(w + 8u*1024*1024);
    short* whh_bf = (short*)(w + 9u*1024*1024);
    unsigned* bar = (unsigned*)(w + 11u*1024*1024);
    float* outp   = (float*)d_out;

    conv_whh<<<512, 256, 0, stream>>>(d_in[4], whh_bf, bar);
    build_xg<<<dim3(16, 64), 256, 0, stream>>>(d_in[2], d_in[3], d_in[5], d_in[6], xg);
    lstm_fused<<<256, 1024, 0, stream>>>(seq, lens, whh_bf, xg, h_even, h_odd, outp, bar);
}